// Round 1
// baseline (566.458 us; speedup 1.0000x reference)
//
#include <hip/hip_runtime.h>
#include <math.h>

// Problem constants (N=512 Clements mesh, L=512 layers, fixed by reference).
#define NPORT  512
#define NLAYER 512
#define NPAIR  256                      // even/odd layer pairs
#define CHUNK  8                        // layer-pairs per LDS stage (was 4)
#define NCHUNK (NPAIR / CHUNK)          // 32 chunks
#define PPL    8                        // coefficient planes per pair
#define PLANES (CHUNK * PPL)            // 64 planes per chunk (64 KB)
#define ATTEN  0.9772372209558107f      // sqrt(10^(-0.2/10))

// Async global->LDS DMA, 16B per lane: LDS dst = uniform base + lane*16.
__device__ __forceinline__ void load_lds16(const float4* g, void* l) {
    __builtin_amdgcn_global_load_lds(
        (const __attribute__((address_space(1))) void*)g,
        (__attribute__((address_space(3))) void*)l, 16, 0, 0);
}

// Lane-shift shuffles via DPP (VALU pipe, no lgkm counter!). This keeps the
// odd-layer boundary exchange OFF the in-order LDS queue so it cannot drain
// the next pair's ds_read prefetch.
// wave_shr:1 (0x138): lane i <- lane i-1 (shfl_up);  lane 0 keeps old.
// wave_shl:1 (0x130): lane i <- lane i+1 (shfl_down); lane 63 keeps old.
__device__ __forceinline__ float dpp_up1(float x) {
    int r = __builtin_amdgcn_update_dpp(__float_as_int(x), __float_as_int(x),
                                        0x138, 0xF, 0xF, false);
    return __int_as_float(r);
}
__device__ __forceinline__ float dpp_down1(float x) {
    int r = __builtin_amdgcn_update_dpp(__float_as_int(x), __float_as_int(x),
                                        0x130, 0xF, 0xF, false);
    return __int_as_float(r);
}

// ---------------------------------------------------------------------------
// Coefficient table: per layer-pair p, 8 planes of 64 float4 (one per lane):
//   planes 0..3: even layer 2p,  lane t slot 4t+j (ports 8t+2j, 8t+2j+1)
//   planes 4..7: odd  layer 2p+1, lane t slot 4t+j (ports 8t+2j+1, 8t+2j+2)
// float4 = {cos(th)*A, sin(th)*A, cos(ph), sin(ph)}; invalid slot (odd,255)
// = identity {1,0,1,0}. The odd-layer LEFT-crossing coefficient for lane t
// (slot 4t-1) is lane t-1's plane-7 value (obtained via dpp_up1).
// ---------------------------------------------------------------------------
__global__ void coeff_kernel(const float* __restrict__ thetas,
                             const float* __restrict__ phis,
                             const int*   __restrict__ mzi_idx,
                             float4*      __restrict__ table) {
    int tid = blockIdx.x * blockDim.x + threadIdx.x;   // 0 .. NPAIR*8*64-1
    if (tid >= NPAIR * PPL * 64) return;
    int lane  = tid & 63;
    int plane = (tid >> 6) & 7;
    int p     = tid >> 9;

    int layer, slot, port_i;
    bool valid;
    if (plane < 4) {                    // even layer
        layer  = 2 * p;
        slot   = 4 * lane + plane;
        port_i = 2 * slot;
        valid  = true;
    } else {                            // odd layer local slots
        layer  = 2 * p + 1;
        slot   = 4 * lane + (plane - 4);
        port_i = 2 * slot + 1;
        valid  = (2 * slot + 2) < NPORT;   // slot 255 -> ports 511/512
    }

    float4 c = make_float4(1.f, 0.f, 1.f, 0.f);
    if (valid) {
        int m  = mzi_idx[layer * NPORT + port_i];
        float th = thetas[m], ph = phis[m];
        c.x = cosf(th) * ATTEN;
        c.y = sinf(th) * ATTEN;
        c.z = cosf(ph);
        c.w = sinf(ph);
    }
    table[(size_t)(p * PPL + plane) * 64 + lane] = c;
}

// ---------------------------------------------------------------------------
// Mesh propagation. 256 threads = 4 waves/block, one batch row per wave;
// lane t holds ports 8t..8t+7 (complex) in registers. 256 blocks = 1/CU.
// Chunk of 8 layer-pairs staged in LDS via global_load_lds double-buffered
// across two 64KB __shared__ arrays (128 KB total, within gfx950's 160 KB);
// consumed with a 2-pair-deep ds_read_b128 rotation. Halving the number of
// chunk boundaries (64->32) halves the barrier+vmcnt-drain and cold-read
// stall classes, which at 1 wave/SIMD are raw exposed latency.
// ---------------------------------------------------------------------------
struct PairCoef {
    float4 e[4];   // even-layer slots
    float4 o[4];   // odd-layer local slots
};

__global__ __launch_bounds__(256, 1)
void mesh_kernel(const float*  __restrict__ x,
                 const float4* __restrict__ table,
                 float*        __restrict__ out,
                 int B) {
    __shared__ float4 bufA[PLANES][64];   // 64 KB
    __shared__ float4 bufB[PLANES][64];   // 64 KB

    const int lane = threadIdx.x & 63;
    const int wid  = threadIdx.x >> 6;    // 0..3
    const int row  = blockIdx.x * 4 + wid;
    const bool live = row < B;

    // Load 8 consecutive real inputs -> complex state (im = 0).
    const float4* xr =
        (const float4*)(x + (size_t)(live ? row : 0) * NPORT) + lane * 2;
    float4 xa = xr[0], xb = xr[1];
    float sr[8] = {xa.x, xa.y, xa.z, xa.w, xb.x, xb.y, xb.z, xb.w};
    float si[8] = {0.f, 0.f, 0.f, 0.f, 0.f, 0.f, 0.f, 0.f};

    // DMA chunk c's 64 planes into buf; wave w takes planes 16w..16w+15.
    auto stage = [&](int c, float4 (*buf)[64]) {
        const float4* g = table + (size_t)c * (PLANES * 64) + lane;
#pragma unroll
        for (int k = 0; k < PLANES / 4; ++k) {
            int pl = wid * (PLANES / 4) + k;
            load_lds16(g + pl * 64, (void*)&buf[pl][0]);
        }
    };

    // One MZI, both ports lane-local; upper port gets the phase.
    auto mzi = [&](const float4 c, int p0, int p1) {
        float ct = c.x, st = c.y, er = c.z, ei = c.w;
        float ur = ct * sr[p0] + st * sr[p1];
        float ui = ct * si[p0] + st * si[p1];
        float lr = ct * sr[p1] - st * sr[p0];
        float li = ct * si[p1] - st * si[p0];
        sr[p0] = er * ur - ei * ui;
        si[p0] = er * ui + ei * ur;
        sr[p1] = lr;
        si[p1] = li;
    };

    auto computePair = [&](const PairCoef& b) {
        // Even layer: ports (2j, 2j+1), all lane-local.
#pragma unroll
        for (int j = 0; j < 4; ++j) mzi(b.e[j], 2 * j, 2 * j + 1);

        // Odd layer. All 6 cross-lane moves via DPP on OLD values (VALU pipe).
        float hr = dpp_down1(sr[0]);      // right neighbor's port 8t+8
        float hi = dpp_down1(si[0]);
        float gr = dpp_up1(sr[7]);        // left neighbor's port 8t-1
        float gi = dpp_up1(si[7]);
        float lc = dpp_up1(b.o[3].x);     // left-crossing ct (slot 4t-1)
        float ls = dpp_up1(b.o[3].y);     // left-crossing st
        float ct4 = (lane > 0) ? lc : 1.f;  // lane 0: port 0 passthrough
        float st4 = (lane > 0) ? ls : 0.f;

        // 3 internal MZIs: ports (2j+1, 2j+2).
#pragma unroll
        for (int j = 0; j < 3; ++j) mzi(b.o[j], 2 * j + 1, 2 * j + 2);

        // Right crossing (upper = local port 7, lower = h): keep upper+phase.
        // Lane 63: slot 255 identity {1,0} -> sr7 passthrough, h unused (x0).
        {
            float ct = b.o[3].x, st = b.o[3].y, er = b.o[3].z, ei = b.o[3].w;
            float ur = ct * sr[7] + st * hr;
            float ui = ct * si[7] + st * hi;
            sr[7] = er * ur - ei * ui;
            si[7] = er * ui + ei * ur;
        }
        // Left crossing (upper = g, lower = local port 0): keep lower.
        {
            float lr = ct4 * sr[0] - st4 * gr;
            float li = ct4 * si[0] - st4 * gi;
            sr[0] = lr;
            si[0] = li;
        }
    };

    auto readPair = [&](const float4 (*buf)[64], int pp) {
        PairCoef b;
#pragma unroll
        for (int j = 0; j < 4; ++j) b.e[j] = buf[pp * PPL + j][lane];
#pragma unroll
        for (int j = 0; j < 4; ++j) b.o[j] = buf[pp * PPL + 4 + j][lane];
        return b;
    };

    // 2-pair-deep rotation: pair p's 8 ds_read_b128 are issued ~2 compute
    // bodies (~480 VALU cycles) before their waitcnt, so steady-state
    // lgkm waits are fully covered even if the scheduler sinks some reads.
    auto computeChunk = [&](const float4 (*buf)[64]) {
        PairCoef A  = readPair(buf, 0);
        PairCoef Bp = readPair(buf, 1);
#pragma unroll
        for (int pp = 0; pp < CHUNK; ++pp) {
            PairCoef Cn;
            if (pp + 2 < CHUNK) Cn = readPair(buf, pp + 2);
            computePair(A);
            A = Bp;
            if (pp + 2 < CHUNK) Bp = Cn;
        }
    };

    stage(0, bufA);
    __syncthreads();

#pragma unroll 1
    for (int c = 0; c < NCHUNK; c += 2) {
        if (c + 1 < NCHUNK) stage(c + 1, bufB);
        computeChunk(bufA);
        __syncthreads();
        if (c + 2 < NCHUNK) stage(c + 2, bufA);
        computeChunk(bufB);
        __syncthreads();
    }

    // Photodetection: |E|^2, vectorized store.
    if (live) {
        float4 o0 = make_float4(sr[0] * sr[0] + si[0] * si[0],
                                sr[1] * sr[1] + si[1] * si[1],
                                sr[2] * sr[2] + si[2] * si[2],
                                sr[3] * sr[3] + si[3] * si[3]);
        float4 o1 = make_float4(sr[4] * sr[4] + si[4] * si[4],
                                sr[5] * sr[5] + si[5] * si[5],
                                sr[6] * sr[6] + si[6] * si[6],
                                sr[7] * sr[7] + si[7] * si[7]);
        float4* op = (float4*)(out + (size_t)row * NPORT) + lane * 2;
        op[0] = o0;
        op[1] = o1;
    }
}

// ---------------------------------------------------------------------------
// Fallback (ws too small for the table): trig inline, slow but correct.
// ---------------------------------------------------------------------------
__global__ __launch_bounds__(64)
void mesh_fallback(const float* __restrict__ x,
                   const float* __restrict__ thetas,
                   const float* __restrict__ phis,
                   const int*   __restrict__ mzi_idx,
                   float*       __restrict__ out) {
    const int lane = threadIdx.x;
    const int row  = blockIdx.x;

    const float4* xr = (const float4*)(x + (size_t)row * NPORT) + lane * 2;
    float4 xa = xr[0], xb = xr[1];
    float sr[8] = {xa.x, xa.y, xa.z, xa.w, xb.x, xb.y, xb.z, xb.w};
    float si[8] = {0.f, 0.f, 0.f, 0.f, 0.f, 0.f, 0.f, 0.f};

    auto mzi = [&](float ct, float st, float er, float ei, int p0, int p1) {
        float ur = ct * sr[p0] + st * sr[p1];
        float ui = ct * si[p0] + st * si[p1];
        float lr = ct * sr[p1] - st * sr[p0];
        float li = ct * si[p1] - st * si[p0];
        sr[p0] = er * ur - ei * ui;
        si[p0] = er * ui + ei * ur;
        sr[p1] = lr;
        si[p1] = li;
    };

    for (int l = 0; l < NLAYER; ++l) {
        if ((l & 1) == 0) {
#pragma unroll
            for (int j = 0; j < 4; ++j) {
                int m = mzi_idx[l * NPORT + (8 * lane + 2 * j)];
                float th = thetas[m], ph = phis[m];
                mzi(cosf(th) * ATTEN, sinf(th) * ATTEN, cosf(ph), sinf(ph),
                    2 * j, 2 * j + 1);
            }
        } else {
            float hr = __shfl_down(sr[0], 1);
            float hi = __shfl_down(si[0], 1);
#pragma unroll
            for (int j = 0; j < 3; ++j) {
                int m = mzi_idx[l * NPORT + (8 * lane + 2 * j + 1)];
                float th = thetas[m], ph = phis[m];
                mzi(cosf(th) * ATTEN, sinf(th) * ATTEN, cosf(ph), sinf(ph),
                    2 * j + 1, 2 * j + 2);
            }
            float ct = 1.f, st = 0.f, er = 1.f, ei = 0.f;
            if (lane < 63) {
                int m = mzi_idx[l * NPORT + (8 * lane + 7)];
                float th = thetas[m], ph = phis[m];
                ct = cosf(th) * ATTEN; st = sinf(th) * ATTEN;
                er = cosf(ph); ei = sinf(ph);
            }
            float ur = ct * sr[7] + st * hr;
            float ui = ct * si[7] + st * hi;
            float lr = ct * hr - st * sr[7];
            float li = ct * hi - st * si[7];
            sr[7] = er * ur - ei * ui;
            si[7] = er * ui + ei * ur;
            float rlr = __shfl_up(lr, 1);
            float rli = __shfl_up(li, 1);
            sr[0] = (lane > 0) ? rlr : sr[0];
            si[0] = (lane > 0) ? rli : si[0];
        }
    }

    float4 o0 = make_float4(sr[0] * sr[0] + si[0] * si[0],
                            sr[1] * sr[1] + si[1] * si[1],
                            sr[2] * sr[2] + si[2] * si[2],
                            sr[3] * sr[3] + si[3] * si[3]);
    float4 o1 = make_float4(sr[4] * sr[4] + si[4] * si[4],
                            sr[5] * sr[5] + si[5] * si[5],
                            sr[6] * sr[6] + si[6] * si[6],
                            sr[7] * sr[7] + si[7] * si[7]);
    float4* op = (float4*)(out + (size_t)row * NPORT) + lane * 2;
    op[0] = o0;
    op[1] = o1;
}

// ---------------------------------------------------------------------------
// Inputs (setup_inputs order): x[B*N] f32, thetas[M] f32, phis[M] f32,
// partner[L*N] i32 (unused), mzi_idx[L*N] i32, role[L*N] i32 (unused).
// ---------------------------------------------------------------------------
extern "C" void kernel_launch(void* const* d_in, const int* in_sizes, int n_in,
                              void* d_out, int out_size, void* d_ws,
                              size_t ws_size, hipStream_t stream) {
    const float* x       = (const float*)d_in[0];
    const float* thetas  = (const float*)d_in[1];
    const float* phis    = (const float*)d_in[2];
    const int*   mzi_idx = (const int*)d_in[4];
    float*       out     = (float*)d_out;

    int B = in_sizes[0] / NPORT;

    const size_t table_bytes = (size_t)NPAIR * PPL * 64 * sizeof(float4); // 2 MiB
    if (ws_size >= table_bytes) {
        float4* table = (float4*)d_ws;
        int nthreads = NPAIR * PPL * 64;
        coeff_kernel<<<(nthreads + 255) / 256, 256, 0, stream>>>(
            thetas, phis, mzi_idx, table);
        int nblk = (B + 3) / 4;
        mesh_kernel<<<nblk, 256, 0, stream>>>(x, table, out, B);
    } else {
        mesh_fallback<<<B, 64, 0, stream>>>(x, thetas, phis, mzi_idx, out);
    }
}

// Round 2
// 201.954 us; speedup vs baseline: 2.8049x; 2.8049x over previous
//
#include <hip/hip_runtime.h>
#include <math.h>

// Problem constants (N=512 Clements mesh, L=512 layers, fixed by reference).
#define NPORT  512
#define NLAYER 512
#define NPAIR  256                      // even/odd layer pairs
#define PPL    8                        // coefficient planes per pair
#define ATTEN  0.9772372209558107f      // sqrt(10^(-0.2/10))

// Lane-shift shuffles via DPP (VALU pipe, no lgkm counter).
// wave_shr:1 (0x138): lane i <- lane i-1 (shfl_up);  lane 0 keeps old.
// wave_shl:1 (0x130): lane i <- lane i+1 (shfl_down); lane 63 keeps old.
__device__ __forceinline__ float dpp_up1(float x) {
    int r = __builtin_amdgcn_update_dpp(__float_as_int(x), __float_as_int(x),
                                        0x138, 0xF, 0xF, false);
    return __int_as_float(r);
}
__device__ __forceinline__ float dpp_down1(float x) {
    int r = __builtin_amdgcn_update_dpp(__float_as_int(x), __float_as_int(x),
                                        0x130, 0xF, 0xF, false);
    return __int_as_float(r);
}

// ---------------------------------------------------------------------------
// Coefficient table: per layer-pair p, 8 planes of 64 float4 (one per lane):
//   planes 0..3: even layer 2p,  lane t slot 4t+j (ports 8t+2j, 8t+2j+1)
//   planes 4..7: odd  layer 2p+1, lane t slot 4t+j (ports 8t+2j+1, 8t+2j+2)
// float4 = {cos(th)*A, sin(th)*A, cos(ph), sin(ph)}; invalid slot (odd,255)
// = identity {1,0,1,0}. The odd-layer LEFT-crossing coefficient for lane t
// (slot 4t-1) is lane t-1's plane-7 value (obtained via dpp_up1).
// ---------------------------------------------------------------------------
__global__ void coeff_kernel(const float* __restrict__ thetas,
                             const float* __restrict__ phis,
                             const int*   __restrict__ mzi_idx,
                             float4*      __restrict__ table) {
    int tid = blockIdx.x * blockDim.x + threadIdx.x;   // 0 .. NPAIR*8*64-1
    if (tid >= NPAIR * PPL * 64) return;
    int lane  = tid & 63;
    int plane = (tid >> 6) & 7;
    int p     = tid >> 9;

    int layer, slot, port_i;
    bool valid;
    if (plane < 4) {                    // even layer
        layer  = 2 * p;
        slot   = 4 * lane + plane;
        port_i = 2 * slot;
        valid  = true;
    } else {                            // odd layer local slots
        layer  = 2 * p + 1;
        slot   = 4 * lane + (plane - 4);
        port_i = 2 * slot + 1;
        valid  = (2 * slot + 2) < NPORT;   // slot 255 -> ports 511/512
    }

    float4 c = make_float4(1.f, 0.f, 1.f, 0.f);
    if (valid) {
        int m  = mzi_idx[layer * NPORT + port_i];
        float th = thetas[m], ph = phis[m];
        c.x = cosf(th) * ATTEN;
        c.y = sinf(th) * ATTEN;
        c.z = cosf(ph);
        c.w = sinf(ph);
    }
    table[(size_t)(p * PPL + plane) * 64 + lane] = c;
}

// ---------------------------------------------------------------------------
// Mesh propagation, LDS-free version. 256 threads = 4 waves/block, one batch
// row per wave; lane t holds ports 8t..8t+7 (complex) in registers.
// 256 blocks = 1/CU. Coefficients are streamed straight from global memory
// into a 4-deep named register pipeline (A,B,C,D - no rotation copies, no
// spill candidate). The 2 MB table fits per-XCD L2 (4 MB) and all blocks
// stream it in the same order, so loads are L2 hits; the 4 co-resident waves
// of a block read identical addresses, so L1 serves most of the redundancy.
// Loads for pair p are issued ~3 compute bodies (~600 VALU cycles) before
// use -> L2-hit latency fully covered by the compiler's counted vmcnt waits.
// No __syncthreads, no LDS, no vmcnt(0) drains anywhere in the hot loop.
// ---------------------------------------------------------------------------
struct PairCoef {
    float4 e[4];   // even-layer slots
    float4 o[4];   // odd-layer local slots
};

__global__ __launch_bounds__(256, 1)
void mesh_kernel(const float*  __restrict__ x,
                 const float4* __restrict__ table,
                 float*        __restrict__ out,
                 int B) {
    const int lane = threadIdx.x & 63;
    const int wid  = threadIdx.x >> 6;    // 0..3
    const int row  = blockIdx.x * 4 + wid;
    const bool live = row < B;

    // Load 8 consecutive real inputs -> complex state (im = 0).
    const float4* xr =
        (const float4*)(x + (size_t)(live ? row : 0) * NPORT) + lane * 2;
    float4 xa = xr[0], xb = xr[1];
    float sr[8] = {xa.x, xa.y, xa.z, xa.w, xb.x, xb.y, xb.z, xb.w};
    float si[8] = {0.f, 0.f, 0.f, 0.f, 0.f, 0.f, 0.f, 0.f};

    // One MZI, both ports lane-local; upper port gets the phase.
    auto mzi = [&](const float4 c, int p0, int p1) {
        float ct = c.x, st = c.y, er = c.z, ei = c.w;
        float ur = ct * sr[p0] + st * sr[p1];
        float ui = ct * si[p0] + st * si[p1];
        float lr = ct * sr[p1] - st * sr[p0];
        float li = ct * si[p1] - st * si[p0];
        sr[p0] = er * ur - ei * ui;
        si[p0] = er * ui + ei * ur;
        sr[p1] = lr;
        si[p1] = li;
    };

    auto computePair = [&](const PairCoef& b) {
        // Even layer: ports (2j, 2j+1), all lane-local.
#pragma unroll
        for (int j = 0; j < 4; ++j) mzi(b.e[j], 2 * j, 2 * j + 1);

        // Odd layer. All 6 cross-lane moves via DPP on OLD values (VALU pipe).
        float hr = dpp_down1(sr[0]);      // right neighbor's port 8t+8
        float hi = dpp_down1(si[0]);
        float gr = dpp_up1(sr[7]);        // left neighbor's port 8t-1
        float gi = dpp_up1(si[7]);
        float lc = dpp_up1(b.o[3].x);     // left-crossing ct (slot 4t-1)
        float ls = dpp_up1(b.o[3].y);     // left-crossing st
        float ct4 = (lane > 0) ? lc : 1.f;  // lane 0: port 0 passthrough
        float st4 = (lane > 0) ? ls : 0.f;

        // 3 internal MZIs: ports (2j+1, 2j+2).
#pragma unroll
        for (int j = 0; j < 3; ++j) mzi(b.o[j], 2 * j + 1, 2 * j + 2);

        // Right crossing (upper = local port 7, lower = h): keep upper+phase.
        // Lane 63: slot 255 identity {1,0} -> sr7 passthrough, h unused (x0).
        {
            float ct = b.o[3].x, st = b.o[3].y, er = b.o[3].z, ei = b.o[3].w;
            float ur = ct * sr[7] + st * hr;
            float ui = ct * si[7] + st * hi;
            sr[7] = er * ur - ei * ui;
            si[7] = er * ui + ei * ur;
        }
        // Left crossing (upper = g, lower = local port 0): keep lower.
        {
            float lr = ct4 * sr[0] - st4 * gr;
            float li = ct4 * si[0] - st4 * gi;
            sr[0] = lr;
            si[0] = li;
        }
    };

    // Load pair p's 8 coefficient float4 straight from global (L2-resident).
    // Pair index is wave-uniform -> scalar base, per-lane +lane*16.
    auto loadPair = [&](int p) {
        PairCoef b;
        const float4* g = table + (size_t)p * (PPL * 64) + lane;
#pragma unroll
        for (int j = 0; j < 4; ++j) b.e[j] = g[j * 64];
#pragma unroll
        for (int j = 0; j < 4; ++j) b.o[j] = g[(4 + j) * 64];
        return b;
    };

    // 4-deep software pipeline with named stages (no struct rotation copies).
    // Prefetch index clamps (scalar cselect) keep the tail in-bounds.
    PairCoef A  = loadPair(0);
    PairCoef Bp = loadPair(1);
    PairCoef C  = loadPair(2);
#pragma unroll 1
    for (int p = 0; p < NPAIR; p += 4) {
        PairCoef D = loadPair(p + 3 < NPAIR ? p + 3 : NPAIR - 1);
        computePair(A);
        A = loadPair(p + 4 < NPAIR ? p + 4 : NPAIR - 1);
        computePair(Bp);
        Bp = loadPair(p + 5 < NPAIR ? p + 5 : NPAIR - 1);
        computePair(C);
        C = loadPair(p + 6 < NPAIR ? p + 6 : NPAIR - 1);
        computePair(D);
    }

    // Photodetection: |E|^2, vectorized store.
    if (live) {
        float4 o0 = make_float4(sr[0] * sr[0] + si[0] * si[0],
                                sr[1] * sr[1] + si[1] * si[1],
                                sr[2] * sr[2] + si[2] * si[2],
                                sr[3] * sr[3] + si[3] * si[3]);
        float4 o1 = make_float4(sr[4] * sr[4] + si[4] * si[4],
                                sr[5] * sr[5] + si[5] * si[5],
                                sr[6] * sr[6] + si[6] * si[6],
                                sr[7] * sr[7] + si[7] * si[7]);
        float4* op = (float4*)(out + (size_t)row * NPORT) + lane * 2;
        op[0] = o0;
        op[1] = o1;
    }
}

// ---------------------------------------------------------------------------
// Fallback (ws too small for the table): trig inline, slow but correct.
// ---------------------------------------------------------------------------
__global__ __launch_bounds__(64)
void mesh_fallback(const float* __restrict__ x,
                   const float* __restrict__ thetas,
                   const float* __restrict__ phis,
                   const int*   __restrict__ mzi_idx,
                   float*       __restrict__ out) {
    const int lane = threadIdx.x;
    const int row  = blockIdx.x;

    const float4* xr = (const float4*)(x + (size_t)row * NPORT) + lane * 2;
    float4 xa = xr[0], xb = xr[1];
    float sr[8] = {xa.x, xa.y, xa.z, xa.w, xb.x, xb.y, xb.z, xb.w};
    float si[8] = {0.f, 0.f, 0.f, 0.f, 0.f, 0.f, 0.f, 0.f};

    auto mzi = [&](float ct, float st, float er, float ei, int p0, int p1) {
        float ur = ct * sr[p0] + st * sr[p1];
        float ui = ct * si[p0] + st * si[p1];
        float lr = ct * sr[p1] - st * sr[p0];
        float li = ct * si[p1] - st * si[p0];
        sr[p0] = er * ur - ei * ui;
        si[p0] = er * ui + ei * ur;
        sr[p1] = lr;
        si[p1] = li;
    };

    for (int l = 0; l < NLAYER; ++l) {
        if ((l & 1) == 0) {
#pragma unroll
            for (int j = 0; j < 4; ++j) {
                int m = mzi_idx[l * NPORT + (8 * lane + 2 * j)];
                float th = thetas[m], ph = phis[m];
                mzi(cosf(th) * ATTEN, sinf(th) * ATTEN, cosf(ph), sinf(ph),
                    2 * j, 2 * j + 1);
            }
        } else {
            float hr = __shfl_down(sr[0], 1);
            float hi = __shfl_down(si[0], 1);
#pragma unroll
            for (int j = 0; j < 3; ++j) {
                int m = mzi_idx[l * NPORT + (8 * lane + 2 * j + 1)];
                float th = thetas[m], ph = phis[m];
                mzi(cosf(th) * ATTEN, sinf(th) * ATTEN, cosf(ph), sinf(ph),
                    2 * j + 1, 2 * j + 2);
            }
            float ct = 1.f, st = 0.f, er = 1.f, ei = 0.f;
            if (lane < 63) {
                int m = mzi_idx[l * NPORT + (8 * lane + 7)];
                float th = thetas[m], ph = phis[m];
                ct = cosf(th) * ATTEN; st = sinf(th) * ATTEN;
                er = cosf(ph); ei = sinf(ph);
            }
            float ur = ct * sr[7] + st * hr;
            float ui = ct * si[7] + st * hi;
            float lr = ct * hr - st * sr[7];
            float li = ct * hi - st * si[7];
            sr[7] = er * ur - ei * ui;
            si[7] = er * ui + ei * ur;
            float rlr = __shfl_up(lr, 1);
            float rli = __shfl_up(li, 1);
            sr[0] = (lane > 0) ? rlr : sr[0];
            si[0] = (lane > 0) ? rli : si[0];
        }
    }

    float4 o0 = make_float4(sr[0] * sr[0] + si[0] * si[0],
                            sr[1] * sr[1] + si[1] * si[1],
                            sr[2] * sr[2] + si[2] * si[2],
                            sr[3] * sr[3] + si[3] * si[3]);
    float4 o1 = make_float4(sr[4] * sr[4] + si[4] * si[4],
                            sr[5] * sr[5] + si[5] * si[5],
                            sr[6] * sr[6] + si[6] * si[6],
                            sr[7] * sr[7] + si[7] * si[7]);
    float4* op = (float4*)(out + (size_t)row * NPORT) + lane * 2;
    op[0] = o0;
    op[1] = o1;
}

// ---------------------------------------------------------------------------
// Inputs (setup_inputs order): x[B*N] f32, thetas[M] f32, phis[M] f32,
// partner[L*N] i32 (unused), mzi_idx[L*N] i32, role[L*N] i32 (unused).
// ---------------------------------------------------------------------------
extern "C" void kernel_launch(void* const* d_in, const int* in_sizes, int n_in,
                              void* d_out, int out_size, void* d_ws,
                              size_t ws_size, hipStream_t stream) {
    const float* x       = (const float*)d_in[0];
    const float* thetas  = (const float*)d_in[1];
    const float* phis    = (const float*)d_in[2];
    const int*   mzi_idx = (const int*)d_in[4];
    float*       out     = (float*)d_out;

    int B = in_sizes[0] / NPORT;

    const size_t table_bytes = (size_t)NPAIR * PPL * 64 * sizeof(float4); // 2 MiB
    if (ws_size >= table_bytes) {
        float4* table = (float4*)d_ws;
        int nthreads = NPAIR * PPL * 64;
        coeff_kernel<<<(nthreads + 255) / 256, 256, 0, stream>>>(
            thetas, phis, mzi_idx, table);
        int nblk = (B + 3) / 4;
        mesh_kernel<<<nblk, 256, 0, stream>>>(x, table, out, B);
    } else {
        mesh_fallback<<<B, 64, 0, stream>>>(x, thetas, phis, mzi_idx, out);
    }
}

// Round 4
// 196.818 us; speedup vs baseline: 2.8781x; 1.0261x over previous
//
#include <hip/hip_runtime.h>
#include <math.h>

// Problem constants (N=512 Clements mesh, L=512 layers, fixed by reference).
#define NPORT  512
#define NLAYER 512
#define NPAIR  256                      // even/odd layer pairs
#define CHUNK  4                        // layer-pairs per LDS stage
#define NCHUNK (NPAIR / CHUNK)          // 64 chunks
#define PPL    8                        // coefficient planes per pair
#define PLANES (CHUNK * PPL)            // 32 planes per chunk (32 KB)
#define ATTEN  0.9772372209558107f      // sqrt(10^(-0.2/10))

// Async global->LDS DMA, 16B per lane: LDS dst = uniform base + lane*16.
__device__ __forceinline__ void load_lds16(const float4* g, void* l) {
    __builtin_amdgcn_global_load_lds(
        (const __attribute__((address_space(1))) void*)g,
        (__attribute__((address_space(3))) void*)l, 16, 0, 0);
}

// Lane-shift shuffles via DPP (VALU pipe, no lgkm counter). This keeps the
// odd-layer boundary exchange OFF the in-order LDS queue so it cannot drain
// the next pair's ds_read prefetch.
// wave_shr:1 (0x138): lane i <- lane i-1 (shfl_up);  lane 0 keeps old.
// wave_shl:1 (0x130): lane i <- lane i+1 (shfl_down); lane 63 keeps old.
__device__ __forceinline__ float dpp_up1(float x) {
    int r = __builtin_amdgcn_update_dpp(__float_as_int(x), __float_as_int(x),
                                        0x138, 0xF, 0xF, false);
    return __int_as_float(r);
}
__device__ __forceinline__ float dpp_down1(float x) {
    int r = __builtin_amdgcn_update_dpp(__float_as_int(x), __float_as_int(x),
                                        0x130, 0xF, 0xF, false);
    return __int_as_float(r);
}

// ---------------------------------------------------------------------------
// Coefficient table: per layer-pair p, 8 planes of 64 float4 (one per lane):
//   planes 0..3: even layer 2p,  lane t slot 4t+j (ports 8t+2j, 8t+2j+1)
//   planes 4..7: odd  layer 2p+1, lane t slot 4t+j (ports 8t+2j+1, 8t+2j+2)
// float4 = {cos(th)*A, sin(th)*A, cos(ph), sin(ph)}; invalid slot (odd,255)
// = identity {1,0,1,0}. The odd-layer LEFT-crossing coefficient for lane t
// (slot 4t-1) is lane t-1's plane-7 value (obtained via dpp_up1).
// ---------------------------------------------------------------------------
__global__ void coeff_kernel(const float* __restrict__ thetas,
                             const float* __restrict__ phis,
                             const int*   __restrict__ mzi_idx,
                             float4*      __restrict__ table) {
    int tid = blockIdx.x * blockDim.x + threadIdx.x;   // 0 .. NPAIR*8*64-1
    if (tid >= NPAIR * PPL * 64) return;
    int lane  = tid & 63;
    int plane = (tid >> 6) & 7;
    int p     = tid >> 9;

    int layer, slot, port_i;
    bool valid;
    if (plane < 4) {                    // even layer
        layer  = 2 * p;
        slot   = 4 * lane + plane;
        port_i = 2 * slot;
        valid  = true;
    } else {                            // odd layer local slots
        layer  = 2 * p + 1;
        slot   = 4 * lane + (plane - 4);
        port_i = 2 * slot + 1;
        valid  = (2 * slot + 2) < NPORT;   // slot 255 -> ports 511/512
    }

    float4 c = make_float4(1.f, 0.f, 1.f, 0.f);
    if (valid) {
        int m  = mzi_idx[layer * NPORT + port_i];
        float th = thetas[m], ph = phis[m];
        c.x = cosf(th) * ATTEN;
        c.y = sinf(th) * ATTEN;
        c.z = cosf(ph);
        c.w = sinf(ph);
    }
    table[(size_t)(p * PPL + plane) * 64 + lane] = c;
}

// ---------------------------------------------------------------------------
// Mesh propagation. 256 threads = 4 waves/block, one batch row per wave;
// lane t holds ports 8t..8t+7 (complex) in registers. 256 blocks = 1/CU.
//
// T3/T4 synchronization (guide m201/m218 pattern): TRIPLE-buffered 32KB chunk
// stages (96 KB LDS), cooperative staging (each wave DMAs 8 of 32 planes via
// global_load_lds), and per-chunk sync = { own-counted s_waitcnt vmcnt(8);
// raw s_barrier; sched_barrier(0) }. The counted vmcnt keeps the NEXT chunk's
// 8 DMAs in flight ACROSS the barrier (raw s_barrier gets no compiler
// vmcnt(0) drain, unlike __syncthreads) -- this deletes the 64 full
// vmcnt(0)+lgkmcnt(0) drains that were the round-0 stall. sched_barrier(0)
// right after the barrier stops ds_reads hoisting above it into other waves'
// not-yet-landed planes (rule #18 discipline).
//
// Slot-reuse safety: chunk c+2 is staged into slot (c+2)%3 only after
// barrier c; any wave past barrier c consumed (hence completed) its reads of
// slot (c-1)%3 == (c+2)%3 during iteration c-1.
// ---------------------------------------------------------------------------
struct PairCoef {
    float4 e[4];   // even-layer slots
    float4 o[4];   // odd-layer local slots
};

__global__ __launch_bounds__(256, 1)
void mesh_kernel(const float*  __restrict__ x,
                 const float4* __restrict__ table,
                 float*        __restrict__ out,
                 int B) {
    __shared__ float4 buf3[3][PLANES][64];   // 3 x 32 KB = 96 KB

    const int lane = threadIdx.x & 63;
    const int wid  = threadIdx.x >> 6;    // 0..3
    const int row  = blockIdx.x * 4 + wid;
    const bool live = row < B;

    // Load 8 consecutive real inputs -> complex state (im = 0).
    const float4* xr =
        (const float4*)(x + (size_t)(live ? row : 0) * NPORT) + lane * 2;
    float4 xa = xr[0], xb = xr[1];
    float sr[8] = {xa.x, xa.y, xa.z, xa.w, xb.x, xb.y, xb.z, xb.w};
    float si[8] = {0.f, 0.f, 0.f, 0.f, 0.f, 0.f, 0.f, 0.f};

    // DMA chunk c's 32 planes into buf; wave w takes planes 8w..8w+7.
    auto stage = [&](int c, float4 (*buf)[64]) {
        const float4* g = table + (size_t)c * (PLANES * 64) + lane;
#pragma unroll
        for (int k = 0; k < PPL; ++k) {
            int pl = wid * PPL + k;
            load_lds16(g + pl * 64, (void*)&buf[pl][0]);
        }
    };

    // One MZI, both ports lane-local; upper port gets the phase.
    auto mzi = [&](const float4 c, int p0, int p1) {
        float ct = c.x, st = c.y, er = c.z, ei = c.w;
        float ur = ct * sr[p0] + st * sr[p1];
        float ui = ct * si[p0] + st * si[p1];
        float lr = ct * sr[p1] - st * sr[p0];
        float li = ct * si[p1] - st * si[p0];
        sr[p0] = er * ur - ei * ui;
        si[p0] = er * ui + ei * ur;
        sr[p1] = lr;
        si[p1] = li;
    };

    auto computePair = [&](const PairCoef& b) {
        // Even layer: ports (2j, 2j+1), all lane-local.
#pragma unroll
        for (int j = 0; j < 4; ++j) mzi(b.e[j], 2 * j, 2 * j + 1);

        // Odd layer. All 6 cross-lane moves via DPP on OLD values (VALU pipe).
        float hr = dpp_down1(sr[0]);      // right neighbor's port 8t+8
        float hi = dpp_down1(si[0]);
        float gr = dpp_up1(sr[7]);        // left neighbor's port 8t-1
        float gi = dpp_up1(si[7]);
        float lc = dpp_up1(b.o[3].x);     // left-crossing ct (slot 4t-1)
        float ls = dpp_up1(b.o[3].y);     // left-crossing st
        float ct4 = (lane > 0) ? lc : 1.f;  // lane 0: port 0 passthrough
        float st4 = (lane > 0) ? ls : 0.f;

        // 3 internal MZIs: ports (2j+1, 2j+2).
#pragma unroll
        for (int j = 0; j < 3; ++j) mzi(b.o[j], 2 * j + 1, 2 * j + 2);

        // Right crossing (upper = local port 7, lower = h): keep upper+phase.
        // Lane 63: slot 255 identity {1,0} -> sr7 passthrough, h unused (x0).
        {
            float ct = b.o[3].x, st = b.o[3].y, er = b.o[3].z, ei = b.o[3].w;
            float ur = ct * sr[7] + st * hr;
            float ui = ct * si[7] + st * hi;
            sr[7] = er * ur - ei * ui;
            si[7] = er * ui + ei * ur;
        }
        // Left crossing (upper = g, lower = local port 0): keep lower.
        {
            float lr = ct4 * sr[0] - st4 * gr;
            float li = ct4 * si[0] - st4 * gi;
            sr[0] = lr;
            si[0] = li;
        }
    };

    auto readPair = [&](const float4 (*buf)[64], int pp) {
        PairCoef b;
#pragma unroll
        for (int j = 0; j < 4; ++j) b.e[j] = buf[pp * PPL + j][lane];
#pragma unroll
        for (int j = 0; j < 4; ++j) b.o[j] = buf[pp * PPL + 4 + j][lane];
        return b;
    };

    // 1-pair-deep rotation: issue pair p+1's 8 ds_read_b128, compute pair p.
    // With DPP shuffles there are no other lgkm ops, so the waitcnt before
    // pair p+1's compute covers reads issued ~200 VALU cycles earlier.
    // All ds_read results are consumed within computePair, so by loop end the
    // wave's lgkm queue is drained -- which is what makes slot reuse safe.
    auto computeChunk = [&](const float4 (*buf)[64]) {
        PairCoef A = readPair(buf, 0);
#pragma unroll
        for (int pp = 0; pp < CHUNK; ++pp) {
            PairCoef Bn;
            if (pp + 1 < CHUNK) Bn = readPair(buf, pp + 1);
            computePair(A);
            if (pp + 1 < CHUNK) A = Bn;
        }
    };

    // Prime: 2 chunks in flight (16 DMAs per wave).
    stage(0, buf3[0]);
    stage(1, buf3[1]);

#pragma unroll 1
    for (int c = 0; c < NCHUNK; ++c) {
        // Own chunk-c DMAs landed (8 newest -- chunk c+1 -- stay in flight).
        if (c + 1 < NCHUNK) {
            asm volatile("s_waitcnt vmcnt(8)" ::: "memory");
        } else {
            asm volatile("s_waitcnt vmcnt(0)" ::: "memory");
        }
        __builtin_amdgcn_s_barrier();          // everyone's chunk c landed
        __builtin_amdgcn_sched_barrier(0);     // no ds_read hoists above
        if (c + 2 < NCHUNK) stage(c + 2, buf3[(c + 2) % 3]);
        computeChunk(buf3[c % 3]);
    }

    // Photodetection: |E|^2, vectorized store.
    if (live) {
        float4 o0 = make_float4(sr[0] * sr[0] + si[0] * si[0],
                                sr[1] * sr[1] + si[1] * si[1],
                                sr[2] * sr[2] + si[2] * si[2],
                                sr[3] * sr[3] + si[3] * si[3]);
        float4 o1 = make_float4(sr[4] * sr[4] + si[4] * si[4],
                                sr[5] * sr[5] + si[5] * si[5],
                                sr[6] * sr[6] + si[6] * si[6],
                                sr[7] * sr[7] + si[7] * si[7]);
        float4* op = (float4*)(out + (size_t)row * NPORT) + lane * 2;
        op[0] = o0;
        op[1] = o1;
    }
}

// ---------------------------------------------------------------------------
// Fallback (ws too small for the table): trig inline, slow but correct.
// ---------------------------------------------------------------------------
__global__ __launch_bounds__(64)
void mesh_fallback(const float* __restrict__ x,
                   const float* __restrict__ thetas,
                   const float* __restrict__ phis,
                   const int*   __restrict__ mzi_idx,
                   float*       __restrict__ out) {
    const int lane = threadIdx.x;
    const int row  = blockIdx.x;

    const float4* xr = (const float4*)(x + (size_t)row * NPORT) + lane * 2;
    float4 xa = xr[0], xb = xr[1];
    float sr[8] = {xa.x, xa.y, xa.z, xa.w, xb.x, xb.y, xb.z, xb.w};
    float si[8] = {0.f, 0.f, 0.f, 0.f, 0.f, 0.f, 0.f, 0.f};

    auto mzi = [&](float ct, float st, float er, float ei, int p0, int p1) {
        float ur = ct * sr[p0] + st * sr[p1];
        float ui = ct * si[p0] + st * si[p1];
        float lr = ct * sr[p1] - st * sr[p0];
        float li = ct * si[p1] - st * si[p0];
        sr[p0] = er * ur - ei * ui;
        si[p0] = er * ui + ei * ur;
        sr[p1] = lr;
        si[p1] = li;
    };

    for (int l = 0; l < NLAYER; ++l) {
        if ((l & 1) == 0) {
#pragma unroll
            for (int j = 0; j < 4; ++j) {
                int m = mzi_idx[l * NPORT + (8 * lane + 2 * j)];
                float th = thetas[m], ph = phis[m];
                mzi(cosf(th) * ATTEN, sinf(th) * ATTEN, cosf(ph), sinf(ph),
                    2 * j, 2 * j + 1);
            }
        } else {
            float hr = __shfl_down(sr[0], 1);
            float hi = __shfl_down(si[0], 1);
#pragma unroll
            for (int j = 0; j < 3; ++j) {
                int m = mzi_idx[l * NPORT + (8 * lane + 2 * j + 1)];
                float th = thetas[m], ph = phis[m];
                mzi(cosf(th) * ATTEN, sinf(th) * ATTEN, cosf(ph), sinf(ph),
                    2 * j + 1, 2 * j + 2);
            }
            float ct = 1.f, st = 0.f, er = 1.f, ei = 0.f;
            if (lane < 63) {
                int m = mzi_idx[l * NPORT + (8 * lane + 7)];
                float th = thetas[m], ph = phis[m];
                ct = cosf(th) * ATTEN; st = sinf(th) * ATTEN;
                er = cosf(ph); ei = sinf(ph);
            }
            float ur = ct * sr[7] + st * hr;
            float ui = ct * si[7] + st * hi;
            float lr = ct * hr - st * sr[7];
            float li = ct * hi - st * si[7];
            sr[7] = er * ur - ei * ui;
            si[7] = er * ui + ei * ur;
            float rlr = __shfl_up(lr, 1);
            float rli = __shfl_up(li, 1);
            sr[0] = (lane > 0) ? rlr : sr[0];
            si[0] = (lane > 0) ? rli : si[0];
        }
    }

    float4 o0 = make_float4(sr[0] * sr[0] + si[0] * si[0],
                            sr[1] * sr[1] + si[1] * si[1],
                            sr[2] * sr[2] + si[2] * si[2],
                            sr[3] * sr[3] + si[3] * si[3]);
    float4 o1 = make_float4(sr[4] * sr[4] + si[4] * si[4],
                            sr[5] * sr[5] + si[5] * si[5],
                            sr[6] * sr[6] + si[6] * si[6],
                            sr[7] * sr[7] + si[7] * si[7]);
    float4* op = (float4*)(out + (size_t)row * NPORT) + lane * 2;
    op[0] = o0;
    op[1] = o1;
}

// ---------------------------------------------------------------------------
// Inputs (setup_inputs order): x[B*N] f32, thetas[M] f32, phis[M] f32,
// partner[L*N] i32 (unused), mzi_idx[L*N] i32, role[L*N] i32 (unused).
// ---------------------------------------------------------------------------
extern "C" void kernel_launch(void* const* d_in, const int* in_sizes, int n_in,
                              void* d_out, int out_size, void* d_ws,
                              size_t ws_size, hipStream_t stream) {
    const float* x       = (const float*)d_in[0];
    const float* thetas  = (const float*)d_in[1];
    const float* phis    = (const float*)d_in[2];
    const int*   mzi_idx = (const int*)d_in[4];
    float*       out     = (float*)d_out;

    int B = in_sizes[0] / NPORT;

    const size_t table_bytes = (size_t)NPAIR * PPL * 64 * sizeof(float4); // 2 MiB
    if (ws_size >= table_bytes) {
        float4* table = (float4*)d_ws;
        int nthreads = NPAIR * PPL * 64;
        coeff_kernel<<<(nthreads + 255) / 256, 256, 0, stream>>>(
            thetas, phis, mzi_idx, table);
        int nblk = (B + 3) / 4;
        mesh_kernel<<<nblk, 256, 0, stream>>>(x, table, out, B);
    } else {
        mesh_fallback<<<B, 64, 0, stream>>>(x, thetas, phis, mzi_idx, out);
    }
}

// Round 5
// 139.209 us; speedup vs baseline: 4.0691x; 1.4138x over previous
//
#include <hip/hip_runtime.h>
#include <math.h>

// Problem constants (N=512 Clements mesh, L=512 layers, fixed by reference).
#define NPORT  512
#define NLAYER 512
#define NPAIR  256                      // even/odd layer pairs
#define CHUNK  4                        // layer-pairs per LDS stage
#define NCHUNK (NPAIR / CHUNK)          // 64 chunks
#define PPL    8                        // coefficient planes per pair
#define PLANES (CHUNK * PPL)            // 32 planes per chunk (32 KB)
#define ATTEN  0.9772372209558107f      // sqrt(10^(-0.2/10))

typedef float f32x2 __attribute__((ext_vector_type(2)));

// Async global->LDS DMA, 16B per lane: LDS dst = uniform base + lane*16.
__device__ __forceinline__ void load_lds16(const float4* g, void* l) {
    __builtin_amdgcn_global_load_lds(
        (const __attribute__((address_space(1))) void*)g,
        (__attribute__((address_space(3))) void*)l, 16, 0, 0);
}

// Lane-shift shuffles via DPP (VALU pipe, no lgkm counter).
// wave_shr:1 (0x138): lane i <- lane i-1 (shfl_up);  lane 0 keeps old.
// wave_shl:1 (0x130): lane i <- lane i+1 (shfl_down); lane 63 keeps old.
__device__ __forceinline__ float dpp_up1(float x) {
    int r = __builtin_amdgcn_update_dpp(__float_as_int(x), __float_as_int(x),
                                        0x138, 0xF, 0xF, false);
    return __int_as_float(r);
}
__device__ __forceinline__ float dpp_down1(float x) {
    int r = __builtin_amdgcn_update_dpp(__float_as_int(x), __float_as_int(x),
                                        0x130, 0xF, 0xF, false);
    return __int_as_float(r);
}

// ---------------------------------------------------------------------------
// Coefficient table: per layer-pair p, 8 planes of 64 float4 (one per lane):
//   planes 0..3: even layer 2p,  lane t slot 4t+j (ports 8t+2j, 8t+2j+1)
//   planes 4..7: odd  layer 2p+1, lane t slot 4t+j (ports 8t+2j+1, 8t+2j+2)
// float4 = {cos(th)*A, sin(th)*A, cos(ph), sin(ph)}; invalid slot (odd,255)
// = identity {1,0,1,0}. The odd-layer LEFT-crossing coefficient for lane t
// (slot 4t-1) is lane t-1's plane-7 value (obtained via dpp_up1).
// ---------------------------------------------------------------------------
__global__ void coeff_kernel(const float* __restrict__ thetas,
                             const float* __restrict__ phis,
                             const int*   __restrict__ mzi_idx,
                             float4*      __restrict__ table) {
    int tid = blockIdx.x * blockDim.x + threadIdx.x;   // 0 .. NPAIR*8*64-1
    if (tid >= NPAIR * PPL * 64) return;
    int lane  = tid & 63;
    int plane = (tid >> 6) & 7;
    int p     = tid >> 9;

    int layer, slot, port_i;
    bool valid;
    if (plane < 4) {                    // even layer
        layer  = 2 * p;
        slot   = 4 * lane + plane;
        port_i = 2 * slot;
        valid  = true;
    } else {                            // odd layer local slots
        layer  = 2 * p + 1;
        slot   = 4 * lane + (plane - 4);
        port_i = 2 * slot + 1;
        valid  = (2 * slot + 2) < NPORT;   // slot 255 -> ports 511/512
    }

    float4 c = make_float4(1.f, 0.f, 1.f, 0.f);
    if (valid) {
        int m  = mzi_idx[layer * NPORT + port_i];
        float th = thetas[m], ph = phis[m];
        c.x = cosf(th) * ATTEN;
        c.y = sinf(th) * ATTEN;
        c.z = cosf(ph);
        c.w = sinf(ph);
    }
    table[(size_t)(p * PPL + plane) * 64 + lane] = c;
}

// ---------------------------------------------------------------------------
// Mesh propagation. EXACT round-0 synchronization skeleton (the empirically
// best: double-buffered 32KB chunks + __syncthreads; every alternative sync
// structure regressed). Two changes, both pure VALU-count reductions:
//
// 1. State held as packed (re,im) f32x2 per port -> elementwise <2 x float>
//    mul/fma, which the gfx950 backend forms into v_pk_fma_f32/v_pk_mul_f32
//    (VOP3P packed fp32), halving math instruction count. Per-element op
//    order is identical to the scalar version -> bit-identical results.
// 2. Copy-free chunk unroll (named c0..c3, no PairCoef rotation copies,
//    which cost 32 v_mov per pair).
// ---------------------------------------------------------------------------
struct PairCoef {
    float4 e[4];   // even-layer slots
    float4 o[4];   // odd-layer local slots
};

__global__ __launch_bounds__(256, 1)
void mesh_kernel(const float*  __restrict__ x,
                 const float4* __restrict__ table,
                 float*        __restrict__ out,
                 int B) {
    __shared__ float4 bufA[PLANES][64];   // 32 KB
    __shared__ float4 bufB[PLANES][64];   // 32 KB

    const int lane = threadIdx.x & 63;
    const int wid  = threadIdx.x >> 6;    // 0..3
    const int row  = blockIdx.x * 4 + wid;
    const bool live = row < B;

    // Load 8 consecutive real inputs -> packed complex state (im = 0).
    const float4* xr =
        (const float4*)(x + (size_t)(live ? row : 0) * NPORT) + lane * 2;
    float4 xa = xr[0], xb = xr[1];
    f32x2 s[8];
    s[0] = (f32x2){xa.x, 0.f}; s[1] = (f32x2){xa.y, 0.f};
    s[2] = (f32x2){xa.z, 0.f}; s[3] = (f32x2){xa.w, 0.f};
    s[4] = (f32x2){xb.x, 0.f}; s[5] = (f32x2){xb.y, 0.f};
    s[6] = (f32x2){xb.z, 0.f}; s[7] = (f32x2){xb.w, 0.f};

    // DMA chunk c's 32 planes into buf; wave w takes planes 8w..8w+7.
    auto stage = [&](int c, float4 (*buf)[64]) {
        const float4* g = table + (size_t)c * (PLANES * 64) + lane;
#pragma unroll
        for (int k = 0; k < PPL; ++k) {
            int pl = wid * PPL + k;
            load_lds16(g + pl * 64, (void*)&buf[pl][0]);
        }
    };

    // One MZI, both ports lane-local; upper port gets the phase.
    // Packed: u = ct*s0 + st*s1; l = ct*s1 - st*s0;
    //         s0' = (er*u.re - ei*u.im, er*u.im + ei*u.re); s1' = l.
    auto mzi = [&](const float4 c, int p0, int p1) {
        f32x2 ct2 = {c.x, c.x}, st2 = {c.y, c.y};
        f32x2 u = ct2 * s[p0] + st2 * s[p1];
        f32x2 l = ct2 * s[p1] - st2 * s[p0];
        f32x2 er2 = {c.z, c.z};
        f32x2 ei2 = {-c.w, c.w};
        f32x2 us  = {u.y, u.x};
        s[p0] = er2 * u + ei2 * us;
        s[p1] = l;
    };

    auto computePair = [&](const PairCoef& b) {
        // Even layer: ports (2j, 2j+1), all lane-local.
#pragma unroll
        for (int j = 0; j < 4; ++j) mzi(b.e[j], 2 * j, 2 * j + 1);

        // Odd layer. All cross-lane moves via DPP on OLD (post-even) values.
        f32x2 h = {dpp_down1(s[0].x), dpp_down1(s[0].y)};  // right nbr port 8t+8
        f32x2 g = {dpp_up1(s[7].x),   dpp_up1(s[7].y)};    // left nbr port 8t-1
        float lc = dpp_up1(b.o[3].x);     // left-crossing ct (slot 4t-1)
        float ls = dpp_up1(b.o[3].y);     // left-crossing st
        float ct4 = (lane > 0) ? lc : 1.f;  // lane 0: port 0 passthrough
        float st4 = (lane > 0) ? ls : 0.f;

        // 3 internal MZIs: ports (2j+1, 2j+2).
#pragma unroll
        for (int j = 0; j < 3; ++j) mzi(b.o[j], 2 * j + 1, 2 * j + 2);

        // Right crossing (upper = local port 7, lower = h): keep upper+phase.
        // Lane 63: slot 255 identity {1,0} -> s[7] passthrough, h unused (x0).
        {
            f32x2 ct2 = {b.o[3].x, b.o[3].x}, st2 = {b.o[3].y, b.o[3].y};
            f32x2 u = ct2 * s[7] + st2 * h;
            f32x2 er2 = {b.o[3].z, b.o[3].z};
            f32x2 ei2 = {-b.o[3].w, b.o[3].w};
            f32x2 us  = {u.y, u.x};
            s[7] = er2 * u + ei2 * us;
        }
        // Left crossing (upper = g, lower = local port 0): keep lower.
        {
            f32x2 ct2 = {ct4, ct4}, st2 = {st4, st4};
            s[0] = ct2 * s[0] - st2 * g;
        }
    };

    auto readPair = [&](const float4 (*buf)[64], int pp) {
        PairCoef b;
#pragma unroll
        for (int j = 0; j < 4; ++j) b.e[j] = buf[pp * PPL + j][lane];
#pragma unroll
        for (int j = 0; j < 4; ++j) b.o[j] = buf[pp * PPL + 4 + j][lane];
        return b;
    };

    // Copy-free rotation: reads for pair p+1 are issued before compute of
    // pair p; named buffers c0..c3, liveness disjoint -> no v_mov copies.
    auto computeChunk = [&](const float4 (*buf)[64]) {
        PairCoef c0 = readPair(buf, 0);
        PairCoef c1 = readPair(buf, 1);
        computePair(c0);
        PairCoef c2 = readPair(buf, 2);
        computePair(c1);
        PairCoef c3 = readPair(buf, 3);
        computePair(c2);
        computePair(c3);
    };

    stage(0, bufA);
    __syncthreads();

#pragma unroll 1
    for (int c = 0; c < NCHUNK; c += 2) {
        if (c + 1 < NCHUNK) stage(c + 1, bufB);
        computeChunk(bufA);
        __syncthreads();
        if (c + 2 < NCHUNK) stage(c + 2, bufA);
        computeChunk(bufB);
        __syncthreads();
    }

    // Photodetection: |E|^2, vectorized store.
    if (live) {
        float4 o0 = make_float4(s[0].x * s[0].x + s[0].y * s[0].y,
                                s[1].x * s[1].x + s[1].y * s[1].y,
                                s[2].x * s[2].x + s[2].y * s[2].y,
                                s[3].x * s[3].x + s[3].y * s[3].y);
        float4 o1 = make_float4(s[4].x * s[4].x + s[4].y * s[4].y,
                                s[5].x * s[5].x + s[5].y * s[5].y,
                                s[6].x * s[6].x + s[6].y * s[6].y,
                                s[7].x * s[7].x + s[7].y * s[7].y);
        float4* op = (float4*)(out + (size_t)row * NPORT) + lane * 2;
        op[0] = o0;
        op[1] = o1;
    }
}

// ---------------------------------------------------------------------------
// Fallback (ws too small for the table): trig inline, slow but correct.
// ---------------------------------------------------------------------------
__global__ __launch_bounds__(64)
void mesh_fallback(const float* __restrict__ x,
                   const float* __restrict__ thetas,
                   const float* __restrict__ phis,
                   const int*   __restrict__ mzi_idx,
                   float*       __restrict__ out) {
    const int lane = threadIdx.x;
    const int row  = blockIdx.x;

    const float4* xr = (const float4*)(x + (size_t)row * NPORT) + lane * 2;
    float4 xa = xr[0], xb = xr[1];
    float sr[8] = {xa.x, xa.y, xa.z, xa.w, xb.x, xb.y, xb.z, xb.w};
    float si[8] = {0.f, 0.f, 0.f, 0.f, 0.f, 0.f, 0.f, 0.f};

    auto mzi = [&](float ct, float st, float er, float ei, int p0, int p1) {
        float ur = ct * sr[p0] + st * sr[p1];
        float ui = ct * si[p0] + st * si[p1];
        float lr = ct * sr[p1] - st * sr[p0];
        float li = ct * si[p1] - st * si[p0];
        sr[p0] = er * ur - ei * ui;
        si[p0] = er * ui + ei * ur;
        sr[p1] = lr;
        si[p1] = li;
    };

    for (int l = 0; l < NLAYER; ++l) {
        if ((l & 1) == 0) {
#pragma unroll
            for (int j = 0; j < 4; ++j) {
                int m = mzi_idx[l * NPORT + (8 * lane + 2 * j)];
                float th = thetas[m], ph = phis[m];
                mzi(cosf(th) * ATTEN, sinf(th) * ATTEN, cosf(ph), sinf(ph),
                    2 * j, 2 * j + 1);
            }
        } else {
            float hr = __shfl_down(sr[0], 1);
            float hi = __shfl_down(si[0], 1);
#pragma unroll
            for (int j = 0; j < 3; ++j) {
                int m = mzi_idx[l * NPORT + (8 * lane + 2 * j + 1)];
                float th = thetas[m], ph = phis[m];
                mzi(cosf(th) * ATTEN, sinf(th) * ATTEN, cosf(ph), sinf(ph),
                    2 * j + 1, 2 * j + 2);
            }
            float ct = 1.f, st = 0.f, er = 1.f, ei = 0.f;
            if (lane < 63) {
                int m = mzi_idx[l * NPORT + (8 * lane + 7)];
                float th = thetas[m], ph = phis[m];
                ct = cosf(th) * ATTEN; st = sinf(th) * ATTEN;
                er = cosf(ph); ei = sinf(ph);
            }
            float ur = ct * sr[7] + st * hr;
            float ui = ct * si[7] + st * hi;
            float lr = ct * hr - st * sr[7];
            float li = ct * hi - st * si[7];
            sr[7] = er * ur - ei * ui;
            si[7] = er * ui + ei * ur;
            float rlr = __shfl_up(lr, 1);
            float rli = __shfl_up(li, 1);
            sr[0] = (lane > 0) ? rlr : sr[0];
            si[0] = (lane > 0) ? rli : si[0];
        }
    }

    float4 o0 = make_float4(sr[0] * sr[0] + si[0] * si[0],
                            sr[1] * sr[1] + si[1] * si[1],
                            sr[2] * sr[2] + si[2] * si[2],
                            sr[3] * sr[3] + si[3] * si[3]);
    float4 o1 = make_float4(sr[4] * sr[4] + si[4] * si[4],
                            sr[5] * sr[5] + si[5] * si[5],
                            sr[6] * sr[6] + si[6] * si[6],
                            sr[7] * sr[7] + si[7] * si[7]);
    float4* op = (float4*)(out + (size_t)row * NPORT) + lane * 2;
    op[0] = o0;
    op[1] = o1;
}

// ---------------------------------------------------------------------------
// Inputs (setup_inputs order): x[B*N] f32, thetas[M] f32, phis[M] f32,
// partner[L*N] i32 (unused), mzi_idx[L*N] i32, role[L*N] i32 (unused).
// ---------------------------------------------------------------------------
extern "C" void kernel_launch(void* const* d_in, const int* in_sizes, int n_in,
                              void* d_out, int out_size, void* d_ws,
                              size_t ws_size, hipStream_t stream) {
    const float* x       = (const float*)d_in[0];
    const float* thetas  = (const float*)d_in[1];
    const float* phis    = (const float*)d_in[2];
    const int*   mzi_idx = (const int*)d_in[4];
    float*       out     = (float*)d_out;

    int B = in_sizes[0] / NPORT;

    const size_t table_bytes = (size_t)NPAIR * PPL * 64 * sizeof(float4); // 2 MiB
    if (ws_size >= table_bytes) {
        float4* table = (float4*)d_ws;
        int nthreads = NPAIR * PPL * 64;
        coeff_kernel<<<(nthreads + 255) / 256, 256, 0, stream>>>(
            thetas, phis, mzi_idx, table);
        int nblk = (B + 3) / 4;
        mesh_kernel<<<nblk, 256, 0, stream>>>(x, table, out, B);
    } else {
        mesh_fallback<<<B, 64, 0, stream>>>(x, thetas, phis, mzi_idx, out);
    }
}

// Round 6
// 134.429 us; speedup vs baseline: 4.2138x; 1.0356x over previous
//
#include <hip/hip_runtime.h>
#include <math.h>

// Problem constants (N=512 Clements mesh, L=512 layers, fixed by reference).
#define NPORT  512
#define NLAYER 512
#define NPAIR  256                      // even/odd layer pairs
#define CHUNK  4                        // layer-pairs per LDS stage
#define NCHUNK (NPAIR / CHUNK)          // 64 chunks
#define PPL    8                        // coefficient planes per pair
#define PLANES (CHUNK * PPL)            // 32 planes per chunk (32 KB)
#define ATTEN  0.9772372209558107f      // sqrt(10^(-0.2/10))

typedef float f32x2 __attribute__((ext_vector_type(2)));
typedef float f32x4 __attribute__((ext_vector_type(4)));

// Async global->LDS DMA, 16B per lane: LDS dst = uniform base + lane*16.
__device__ __forceinline__ void load_lds16(const void* g, void* l) {
    __builtin_amdgcn_global_load_lds(
        (const __attribute__((address_space(1))) void*)g,
        (__attribute__((address_space(3))) void*)l, 16, 0, 0);
}

// Lane-shift shuffles via DPP (VALU pipe, no lgkm counter).
// wave_shr:1 (0x138): lane i <- lane i-1 (shfl_up);  lane 0 keeps old.
// wave_shl:1 (0x130): lane i <- lane i+1 (shfl_down); lane 63 keeps old.
__device__ __forceinline__ float dpp_up1(float x) {
    int r = __builtin_amdgcn_update_dpp(__float_as_int(x), __float_as_int(x),
                                        0x138, 0xF, 0xF, false);
    return __int_as_float(r);
}
__device__ __forceinline__ float dpp_down1(float x) {
    int r = __builtin_amdgcn_update_dpp(__float_as_int(x), __float_as_int(x),
                                        0x130, 0xF, 0xF, false);
    return __int_as_float(r);
}

// ---------------------------------------------------------------------------
// VOP3P packed-fp32 MZI, zero-mov form. cs = (ct,st), ep = (er,ei) are the
// NATURAL register pairs of the coefficient float4 (no splat materialization:
// op_sel/op_sel_hi select lo/hi halves per output lane; neg_lo/neg_hi fold
// the subtractions). Math order per element is mul-then-fma, identical to the
// scalar/packed versions -> bit-identical results.
//   u  = ct*s0 + st*s1
//   l  = ct*s1 - st*s0
//   s0 = (er*u.re - ei*u.im, er*u.im + ei*u.re);  s1 = l
// ---------------------------------------------------------------------------
__device__ __forceinline__ void mzi_pk(f32x2 cs, f32x2 ep,
                                       f32x2& s0, f32x2& s1) {
    f32x2 t, u, t2, l, t3, r;
    asm("v_pk_mul_f32 %0, %1, %2 op_sel:[0,0] op_sel_hi:[0,1]"
        : "=v"(t) : "v"(cs), "v"(s0));
    asm("v_pk_fma_f32 %0, %1, %2, %3 op_sel:[1,0,0] op_sel_hi:[1,1,1]"
        : "=v"(u) : "v"(cs), "v"(s1), "v"(t));
    asm("v_pk_mul_f32 %0, %1, %2 op_sel:[0,0] op_sel_hi:[0,1]"
        : "=v"(t2) : "v"(cs), "v"(s1));
    asm("v_pk_fma_f32 %0, %1, %2, %3 op_sel:[1,0,0] op_sel_hi:[1,1,1] "
        "neg_lo:[1,0,0] neg_hi:[1,0,0]"
        : "=v"(l) : "v"(cs), "v"(s0), "v"(t2));
    asm("v_pk_mul_f32 %0, %1, %2 op_sel:[0,0] op_sel_hi:[0,1]"
        : "=v"(t3) : "v"(ep), "v"(u));
    asm("v_pk_fma_f32 %0, %1, %2, %3 op_sel:[1,1,0] op_sel_hi:[1,0,1] "
        "neg_lo:[1,0,0] neg_hi:[0,0,0]"
        : "=v"(r) : "v"(ep), "v"(u), "v"(t3));
    s0 = r;
    s1 = l;
}

// Right-crossing variant: keep only the (phased) upper output.
__device__ __forceinline__ void mzi_keep_upper(f32x2 cs, f32x2 ep,
                                               f32x2& s0, f32x2 h) {
    f32x2 t, u, t3, r;
    asm("v_pk_mul_f32 %0, %1, %2 op_sel:[0,0] op_sel_hi:[0,1]"
        : "=v"(t) : "v"(cs), "v"(s0));
    asm("v_pk_fma_f32 %0, %1, %2, %3 op_sel:[1,0,0] op_sel_hi:[1,1,1]"
        : "=v"(u) : "v"(cs), "v"(h), "v"(t));
    asm("v_pk_mul_f32 %0, %1, %2 op_sel:[0,0] op_sel_hi:[0,1]"
        : "=v"(t3) : "v"(ep), "v"(u));
    asm("v_pk_fma_f32 %0, %1, %2, %3 op_sel:[1,1,0] op_sel_hi:[1,0,1] "
        "neg_lo:[1,0,0] neg_hi:[0,0,0]"
        : "=v"(r) : "v"(ep), "v"(u), "v"(t3));
    s0 = r;
}

// ---------------------------------------------------------------------------
// Coefficient table: per layer-pair p, 8 planes of 64 float4 (one per lane):
//   planes 0..3: even layer 2p,  lane t slot 4t+j (ports 8t+2j, 8t+2j+1)
//   planes 4..7: odd  layer 2p+1, lane t slot 4t+j (ports 8t+2j+1, 8t+2j+2)
// float4 = {cos(th)*A, sin(th)*A, cos(ph), sin(ph)}; invalid slot (odd,255)
// = identity {1,0,1,0}. The odd-layer LEFT-crossing coefficient for lane t
// (slot 4t-1) is lane t-1's plane-7 value (obtained via dpp_up1).
// ---------------------------------------------------------------------------
__global__ void coeff_kernel(const float* __restrict__ thetas,
                             const float* __restrict__ phis,
                             const int*   __restrict__ mzi_idx,
                             float4*      __restrict__ table) {
    int tid = blockIdx.x * blockDim.x + threadIdx.x;   // 0 .. NPAIR*8*64-1
    if (tid >= NPAIR * PPL * 64) return;
    int lane  = tid & 63;
    int plane = (tid >> 6) & 7;
    int p     = tid >> 9;

    int layer, slot, port_i;
    bool valid;
    if (plane < 4) {                    // even layer
        layer  = 2 * p;
        slot   = 4 * lane + plane;
        port_i = 2 * slot;
        valid  = true;
    } else {                            // odd layer local slots
        layer  = 2 * p + 1;
        slot   = 4 * lane + (plane - 4);
        port_i = 2 * slot + 1;
        valid  = (2 * slot + 2) < NPORT;   // slot 255 -> ports 511/512
    }

    float4 c = make_float4(1.f, 0.f, 1.f, 0.f);
    if (valid) {
        int m  = mzi_idx[layer * NPORT + port_i];
        float th = thetas[m], ph = phis[m];
        c.x = cosf(th) * ATTEN;
        c.y = sinf(th) * ATTEN;
        c.z = cosf(ph);
        c.w = sinf(ph);
    }
    table[(size_t)(p * PPL + plane) * 64 + lane] = c;
}

// ---------------------------------------------------------------------------
// Mesh propagation. EXACT round-0 synchronization skeleton (empirically best:
// double-buffered 32KB chunks + __syncthreads; every alternative regressed).
// Round-6 change: MZI math in explicit VOP3P inline asm (6 instr/MZI, zero
// splat movs) -- register-only asm, no memory hazards.
// ---------------------------------------------------------------------------
struct PairCoef {
    f32x4 e[4];   // even-layer slots
    f32x4 o[4];   // odd-layer local slots
};

__device__ __forceinline__ f32x2 lo2(f32x4 v) {
    return __builtin_shufflevector(v, v, 0, 1);
}
__device__ __forceinline__ f32x2 hi2(f32x4 v) {
    return __builtin_shufflevector(v, v, 2, 3);
}

__global__ __launch_bounds__(256, 1)
void mesh_kernel(const float*  __restrict__ x,
                 const float4* __restrict__ table,
                 float*        __restrict__ out,
                 int B) {
    __shared__ f32x4 bufA[PLANES][64];   // 32 KB
    __shared__ f32x4 bufB[PLANES][64];   // 32 KB

    const int lane = threadIdx.x & 63;
    const int wid  = threadIdx.x >> 6;    // 0..3
    const int row  = blockIdx.x * 4 + wid;
    const bool live = row < B;

    // Load 8 consecutive real inputs -> packed complex state (im = 0).
    const float4* xr =
        (const float4*)(x + (size_t)(live ? row : 0) * NPORT) + lane * 2;
    float4 xa = xr[0], xb = xr[1];
    f32x2 s[8];
    s[0] = (f32x2){xa.x, 0.f}; s[1] = (f32x2){xa.y, 0.f};
    s[2] = (f32x2){xa.z, 0.f}; s[3] = (f32x2){xa.w, 0.f};
    s[4] = (f32x2){xb.x, 0.f}; s[5] = (f32x2){xb.y, 0.f};
    s[6] = (f32x2){xb.z, 0.f}; s[7] = (f32x2){xb.w, 0.f};

    // DMA chunk c's 32 planes into buf; wave w takes planes 8w..8w+7.
    auto stage = [&](int c, f32x4 (*buf)[64]) {
        const float4* g = table + (size_t)c * (PLANES * 64) + lane;
#pragma unroll
        for (int k = 0; k < PPL; ++k) {
            int pl = wid * PPL + k;
            load_lds16((const void*)(g + pl * 64), (void*)&buf[pl][0]);
        }
    };

    auto computePair = [&](const PairCoef& b) {
        // Even layer: ports (2j, 2j+1), all lane-local.
#pragma unroll
        for (int j = 0; j < 4; ++j)
            mzi_pk(lo2(b.e[j]), hi2(b.e[j]), s[2 * j], s[2 * j + 1]);

        // Odd layer. All cross-lane moves via DPP on OLD (post-even) values.
        f32x2 h = {dpp_down1(s[0].x), dpp_down1(s[0].y)};  // right nbr 8t+8
        f32x2 g = {dpp_up1(s[7].x),   dpp_up1(s[7].y)};    // left nbr 8t-1
        float lc = dpp_up1(b.o[3][0]);    // left-crossing ct (slot 4t-1)
        float ls = dpp_up1(b.o[3][1]);    // left-crossing st
        float ct4 = (lane > 0) ? lc : 1.f;  // lane 0: port 0 passthrough
        float st4 = (lane > 0) ? ls : 0.f;

        // 3 internal MZIs: ports (2j+1, 2j+2).
#pragma unroll
        for (int j = 0; j < 3; ++j)
            mzi_pk(lo2(b.o[j]), hi2(b.o[j]), s[2 * j + 1], s[2 * j + 2]);

        // Right crossing (upper = local port 7, lower = h): keep upper+phase.
        // Lane 63: slot 255 identity {1,0} -> s[7] passthrough, h unused (x0).
        mzi_keep_upper(lo2(b.o[3]), hi2(b.o[3]), s[7], h);

        // Left crossing (upper = g, lower = local port 0): keep lower.
        {
            float lr = ct4 * s[0].x - st4 * g.x;
            float li = ct4 * s[0].y - st4 * g.y;
            s[0] = (f32x2){lr, li};
        }
    };

    auto readPair = [&](const f32x4 (*buf)[64], int pp) {
        PairCoef b;
#pragma unroll
        for (int j = 0; j < 4; ++j) b.e[j] = buf[pp * PPL + j][lane];
#pragma unroll
        for (int j = 0; j < 4; ++j) b.o[j] = buf[pp * PPL + 4 + j][lane];
        return b;
    };

    // Copy-free rotation: reads for pair p+1 are issued before compute of
    // pair p; named buffers c0..c3, liveness disjoint -> no v_mov copies.
    auto computeChunk = [&](const f32x4 (*buf)[64]) {
        PairCoef c0 = readPair(buf, 0);
        PairCoef c1 = readPair(buf, 1);
        computePair(c0);
        PairCoef c2 = readPair(buf, 2);
        computePair(c1);
        PairCoef c3 = readPair(buf, 3);
        computePair(c2);
        computePair(c3);
    };

    stage(0, bufA);
    __syncthreads();

#pragma unroll 1
    for (int c = 0; c < NCHUNK; c += 2) {
        if (c + 1 < NCHUNK) stage(c + 1, bufB);
        computeChunk(bufA);
        __syncthreads();
        if (c + 2 < NCHUNK) stage(c + 2, bufA);
        computeChunk(bufB);
        __syncthreads();
    }

    // Photodetection: |E|^2, vectorized store.
    if (live) {
        float4 o0 = make_float4(s[0].x * s[0].x + s[0].y * s[0].y,
                                s[1].x * s[1].x + s[1].y * s[1].y,
                                s[2].x * s[2].x + s[2].y * s[2].y,
                                s[3].x * s[3].x + s[3].y * s[3].y);
        float4 o1 = make_float4(s[4].x * s[4].x + s[4].y * s[4].y,
                                s[5].x * s[5].x + s[5].y * s[5].y,
                                s[6].x * s[6].x + s[6].y * s[6].y,
                                s[7].x * s[7].x + s[7].y * s[7].y);
        float4* op = (float4*)(out + (size_t)row * NPORT) + lane * 2;
        op[0] = o0;
        op[1] = o1;
    }
}

// ---------------------------------------------------------------------------
// Fallback (ws too small for the table): trig inline, slow but correct.
// ---------------------------------------------------------------------------
__global__ __launch_bounds__(64)
void mesh_fallback(const float* __restrict__ x,
                   const float* __restrict__ thetas,
                   const float* __restrict__ phis,
                   const int*   __restrict__ mzi_idx,
                   float*       __restrict__ out) {
    const int lane = threadIdx.x;
    const int row  = blockIdx.x;

    const float4* xr = (const float4*)(x + (size_t)row * NPORT) + lane * 2;
    float4 xa = xr[0], xb = xr[1];
    float sr[8] = {xa.x, xa.y, xa.z, xa.w, xb.x, xb.y, xb.z, xb.w};
    float si[8] = {0.f, 0.f, 0.f, 0.f, 0.f, 0.f, 0.f, 0.f};

    auto mzi = [&](float ct, float st, float er, float ei, int p0, int p1) {
        float ur = ct * sr[p0] + st * sr[p1];
        float ui = ct * si[p0] + st * si[p1];
        float lr = ct * sr[p1] - st * sr[p0];
        float li = ct * si[p1] - st * si[p0];
        sr[p0] = er * ur - ei * ui;
        si[p0] = er * ui + ei * ur;
        sr[p1] = lr;
        si[p1] = li;
    };

    for (int l = 0; l < NLAYER; ++l) {
        if ((l & 1) == 0) {
#pragma unroll
            for (int j = 0; j < 4; ++j) {
                int m = mzi_idx[l * NPORT + (8 * lane + 2 * j)];
                float th = thetas[m], ph = phis[m];
                mzi(cosf(th) * ATTEN, sinf(th) * ATTEN, cosf(ph), sinf(ph),
                    2 * j, 2 * j + 1);
            }
        } else {
            float hr = __shfl_down(sr[0], 1);
            float hi = __shfl_down(si[0], 1);
#pragma unroll
            for (int j = 0; j < 3; ++j) {
                int m = mzi_idx[l * NPORT + (8 * lane + 2 * j + 1)];
                float th = thetas[m], ph = phis[m];
                mzi(cosf(th) * ATTEN, sinf(th) * ATTEN, cosf(ph), sinf(ph),
                    2 * j + 1, 2 * j + 2);
            }
            float ct = 1.f, st = 0.f, er = 1.f, ei = 0.f;
            if (lane < 63) {
                int m = mzi_idx[l * NPORT + (8 * lane + 7)];
                float th = thetas[m], ph = phis[m];
                ct = cosf(th) * ATTEN; st = sinf(th) * ATTEN;
                er = cosf(ph); ei = sinf(ph);
            }
            float ur = ct * sr[7] + st * hr;
            float ui = ct * si[7] + st * hi;
            float lr = ct * hr - st * sr[7];
            float li = ct * hi - st * si[7];
            sr[7] = er * ur - ei * ui;
            si[7] = er * ui + ei * ur;
            float rlr = __shfl_up(lr, 1);
            float rli = __shfl_up(li, 1);
            sr[0] = (lane > 0) ? rlr : sr[0];
            si[0] = (lane > 0) ? rli : si[0];
        }
    }

    float4 o0 = make_float4(sr[0] * sr[0] + si[0] * si[0],
                            sr[1] * sr[1] + si[1] * si[1],
                            sr[2] * sr[2] + si[2] * si[2],
                            sr[3] * sr[3] + si[3] * si[3]);
    float4 o1 = make_float4(sr[4] * sr[4] + si[4] * si[4],
                            sr[5] * sr[5] + si[5] * si[5],
                            sr[6] * sr[6] + si[6] * si[6],
                            sr[7] * sr[7] + si[7] * si[7]);
    float4* op = (float4*)(out + (size_t)row * NPORT) + lane * 2;
    op[0] = o0;
    op[1] = o1;
}

// ---------------------------------------------------------------------------
// Inputs (setup_inputs order): x[B*N] f32, thetas[M] f32, phis[M] f32,
// partner[L*N] i32 (unused), mzi_idx[L*N] i32, role[L*N] i32 (unused).
// ---------------------------------------------------------------------------
extern "C" void kernel_launch(void* const* d_in, const int* in_sizes, int n_in,
                              void* d_out, int out_size, void* d_ws,
                              size_t ws_size, hipStream_t stream) {
    const float* x       = (const float*)d_in[0];
    const float* thetas  = (const float*)d_in[1];
    const float* phis    = (const float*)d_in[2];
    const int*   mzi_idx = (const int*)d_in[4];
    float*       out     = (float*)d_out;

    int B = in_sizes[0] / NPORT;

    const size_t table_bytes = (size_t)NPAIR * PPL * 64 * sizeof(float4); // 2 MiB
    if (ws_size >= table_bytes) {
        float4* table = (float4*)d_ws;
        int nthreads = NPAIR * PPL * 64;
        coeff_kernel<<<(nthreads + 255) / 256, 256, 0, stream>>>(
            thetas, phis, mzi_idx, table);
        int nblk = (B + 3) / 4;
        mesh_kernel<<<nblk, 256, 0, stream>>>(x, table, out, B);
    } else {
        mesh_fallback<<<B, 64, 0, stream>>>(x, thetas, phis, mzi_idx, out);
    }
}